// Round 3
// baseline (382.984 us; speedup 1.0000x reference)
//
#include <hip/hip_runtime.h>
#include <hip/hip_bf16.h>

// CustomModel_60851096649964: two-stage biased top-k attention, folded weights.
// R3: revert R2 fusion (occupancy disaster). Chain of lean kernels:
//  precompute -> gemm1(qS) -> attn_cross2 (MFMA, bf16 LDS) -> gemm64(y)
//  -> gemm(yS2) -> attn_self -> gemm64(out)

typedef __attribute__((ext_vector_type(4))) float f32x4;
typedef __attribute__((ext_vector_type(8))) short bf16x8v;
typedef __attribute__((ext_vector_type(4))) short short4v;

#define BT_N 2880
#define A_N  10
#define M_N  350
#define BQ_N (BT_N * A_N)   // 28800
#define DIMC 128

static __device__ __forceinline__ short f2b(float x) {
    __hip_bfloat16 b = __float2bfloat16(x);
    return __builtin_bit_cast(short, b);
}
static __device__ __forceinline__ float b2f(short s) {
    unsigned u = ((unsigned)(unsigned short)s) << 16;
    return __builtin_bit_cast(float, u);
}

// ---------------------------------------------------------------------------
// K0: folded per-head matrices (bf16, transposed for B^T GEMM). Unchanged.
// ---------------------------------------------------------------------------
__global__ __launch_bounds__(256) void precompute_mats(
    const float* __restrict__ Wq, const float* __restrict__ Wk,
    const float* __restrict__ Wv, const float* __restrict__ Wcp,
    const float* __restrict__ Wc, const float* __restrict__ Wsp,
    short* __restrict__ S1t, short* __restrict__ VP1t,
    short* __restrict__ S2t, short* __restrict__ VP2t)
{
    int gid = blockIdx.x * 256 + threadIdx.x;
    int mat = gid >> 17;
    int idx = gid & 131071;
    float acc = 0.f;
    if (mat == 0) {
        int n = idx >> 7, c = idx & 127;
        int h = n >> 7, d = n & 127;
        #pragma unroll
        for (int t = 0; t < 16; ++t)
            acc += Wq[c * 128 + h * 16 + t] * Wk[d * 128 + h * 16 + t];
        S1t[idx] = f2b(acc * 0.25f);
    } else if (mat == 1) {
        int d = idx >> 10, o = idx & 1023;
        int h = o >> 7, c = o & 127;
        #pragma unroll
        for (int t = 0; t < 16; ++t)
            acc += Wv[c * 128 + h * 16 + t] * Wcp[(h * 16 + t) * 128 + d];
        VP1t[idx] = f2b(acc);
    } else if (mat == 2) {
        int n = idx >> 7, c = idx & 127;
        int h = n >> 7, d = n & 127;
        #pragma unroll
        for (int t = 0; t < 16; ++t)
            acc += Wc[c * 384 + h * 16 + t] * Wc[d * 384 + 128 + h * 16 + t];
        S2t[idx] = f2b(acc * 0.25f);
    } else {
        int d = idx >> 10, o = idx & 1023;
        int h = o >> 7, c = o & 127;
        #pragma unroll
        for (int t = 0; t < 16; ++t)
            acc += Wc[c * 384 + 256 + h * 16 + t] * Wsp[(h * 16 + t) * 128 + d];
        VP2t[idx] = f2b(acc);
    }
}

// ---------------------------------------------------------------------------
// bf16 MFMA GEMM, C[M,N] = A[M,K] @ Bt^T. BM=BN=128, BK=64.
// ---------------------------------------------------------------------------
template<bool AF32, bool CF32>
__global__ __launch_bounds__(256) void gemm_bt(
    const void* __restrict__ Ap, const short* __restrict__ Bt,
    void* __restrict__ Cp, int M, int N, int K)
{
    __shared__ short As[128][72];
    __shared__ short Bs[128][72];
    const int tid  = threadIdx.x;
    const int bm   = blockIdx.y << 7, bn = blockIdx.x << 7;
    const int wave = tid >> 6, lane = tid & 63;
    const int wm   = (wave >> 1) << 6, wn = (wave & 1) << 6;
    const int row16 = lane & 15, kq = (lane >> 4) << 3;
    f32x4 acc[4][4] = {};

    for (int k0 = 0; k0 < K; k0 += 64) {
        if (AF32) {
            const float* A = (const float*)Ap;
            #pragma unroll
            for (int i = 0; i < 8; ++i) {
                int f = (i << 8) + tid;
                int r = f >> 4, c = (f & 15) << 2;
                f32x4 v = *(const f32x4*)(A + (size_t)(bm + r) * K + k0 + c);
                short4v t;
                t.x = f2b(v.x); t.y = f2b(v.y); t.z = f2b(v.z); t.w = f2b(v.w);
                *(short4v*)&As[r][c] = t;
            }
        } else {
            const short* A = (const short*)Ap;
            #pragma unroll
            for (int i = 0; i < 4; ++i) {
                int g = (i << 8) + tid;
                int r = g >> 3, c = (g & 7) << 3;
                *(bf16x8v*)&As[r][c] = *(const bf16x8v*)(A + (size_t)(bm + r) * K + k0 + c);
            }
        }
        #pragma unroll
        for (int i = 0; i < 4; ++i) {
            int g = (i << 8) + tid;
            int r = g >> 3, c = (g & 7) << 3;
            *(bf16x8v*)&Bs[r][c] = *(const bf16x8v*)(Bt + (size_t)(bn + r) * K + k0 + c);
        }
        __syncthreads();
        #pragma unroll
        for (int kk = 0; kk < 64; kk += 32) {
            bf16x8v afr[4], bfr[4];
            #pragma unroll
            for (int mi = 0; mi < 4; ++mi)
                afr[mi] = *(const bf16x8v*)&As[wm + (mi << 4) + row16][kq + kk];
            #pragma unroll
            for (int ni = 0; ni < 4; ++ni)
                bfr[ni] = *(const bf16x8v*)&Bs[wn + (ni << 4) + row16][kq + kk];
            #pragma unroll
            for (int mi = 0; mi < 4; ++mi)
                #pragma unroll
                for (int ni = 0; ni < 4; ++ni)
                    acc[mi][ni] = __builtin_amdgcn_mfma_f32_16x16x32_bf16(
                        afr[mi], bfr[ni], acc[mi][ni], 0, 0, 0);
        }
        __syncthreads();
    }

    const int col = lane & 15, rb = (lane >> 4) << 2;
    #pragma unroll
    for (int mi = 0; mi < 4; ++mi)
        #pragma unroll
        for (int ni = 0; ni < 4; ++ni)
            #pragma unroll
            for (int r = 0; r < 4; ++r) {
                int rr = bm + wm + (mi << 4) + rb + r;
                int cc = bn + wn + (ni << 4) + col;
                float v = acc[mi][ni][r];
                if (CF32) ((float*)Cp)[(size_t)rr * N + cc] = v;
                else      ((short*)Cp)[(size_t)rr * N + cc] = f2b(v);
            }
}

// ---------------------------------------------------------------------------
// BM=64 variant for the N=128 GEMMs (grid 450 -> better device fill).
// A is bf16. C fp32 or bf16.
// ---------------------------------------------------------------------------
template<bool CF32>
__global__ __launch_bounds__(256) void gemm_bt64(
    const short* __restrict__ Ap, const short* __restrict__ Bt,
    void* __restrict__ Cp, int M, int N, int K)
{
    __shared__ short As[64][72];
    __shared__ short Bs[128][72];
    const int tid  = threadIdx.x;
    const int bm   = blockIdx.y << 6, bn = blockIdx.x << 7;
    const int wave = tid >> 6, lane = tid & 63;
    const int wm   = (wave >> 1) << 5, wn = (wave & 1) << 6;
    const int row16 = lane & 15, kq = (lane >> 4) << 3;
    f32x4 acc[2][4] = {};

    for (int k0 = 0; k0 < K; k0 += 64) {
        #pragma unroll
        for (int i = 0; i < 2; ++i) {
            int g = (i << 8) + tid;
            int r = g >> 3, c = (g & 7) << 3;
            *(bf16x8v*)&As[r][c] = *(const bf16x8v*)(Ap + (size_t)(bm + r) * K + k0 + c);
        }
        #pragma unroll
        for (int i = 0; i < 4; ++i) {
            int g = (i << 8) + tid;
            int r = g >> 3, c = (g & 7) << 3;
            *(bf16x8v*)&Bs[r][c] = *(const bf16x8v*)(Bt + (size_t)(bn + r) * K + k0 + c);
        }
        __syncthreads();
        #pragma unroll
        for (int kk = 0; kk < 64; kk += 32) {
            bf16x8v afr[2], bfr[4];
            #pragma unroll
            for (int mi = 0; mi < 2; ++mi)
                afr[mi] = *(const bf16x8v*)&As[wm + (mi << 4) + row16][kq + kk];
            #pragma unroll
            for (int ni = 0; ni < 4; ++ni)
                bfr[ni] = *(const bf16x8v*)&Bs[wn + (ni << 4) + row16][kq + kk];
            #pragma unroll
            for (int mi = 0; mi < 2; ++mi)
                #pragma unroll
                for (int ni = 0; ni < 4; ++ni)
                    acc[mi][ni] = __builtin_amdgcn_mfma_f32_16x16x32_bf16(
                        afr[mi], bfr[ni], acc[mi][ni], 0, 0, 0);
        }
        __syncthreads();
    }

    const int col = lane & 15, rb = (lane >> 4) << 2;
    #pragma unroll
    for (int mi = 0; mi < 2; ++mi)
        #pragma unroll
        for (int ni = 0; ni < 4; ++ni)
            #pragma unroll
            for (int r = 0; r < 4; ++r) {
                int rr = bm + wm + (mi << 4) + rb + r;
                int cc = bn + wn + (ni << 4) + col;
                float v = acc[mi][ni][r];
                if (CF32) ((float*)Cp)[(size_t)rr * N + cc] = v;
                else      ((short*)Cp)[(size_t)rr * N + cc] = f2b(v);
            }
}

// ---------------------------------------------------------------------------
// Cross attention v2: MFMA score + combine, bf16 LDS. One (b,q) per block.
// scores[32 keys, 8 heads] = mfma(m_rows, qS_heads); softmax over keys;
// u[h,0:128] = mfma(w[h,keys], m^T).  XCD-swizzled for per-b m L2 reuse.
// ---------------------------------------------------------------------------
__global__ __launch_bounds__(256) void attn_cross2(
    const float* __restrict__ m_token, const short* __restrict__ qS,
    const float* __restrict__ pe, const int* __restrict__ rel,
    short* __restrict__ u)
{
    __shared__ short mr[32][136];    // gathered m rows, bf16 (score A operand)
    __shared__ short mT[128][40];    // transposed m (combine B operand)
    __shared__ short qsr[16][136];   // qS per head (score B), rows 8..15 zero
    __shared__ float sc[2][32][20];  // partial scores [khalf][key][head]
    __shared__ short wts[16][40];    // softmax weights bf16 [head][key]
    __shared__ float peL[256];       // pe[key][head]
    __shared__ short uL[8][136];     // output bounce
    __shared__ int   selk[32];

    // bijective XCD swizzle: 28800 = 8 xcd * 360 b * 10 q
    const int phys = blockIdx.x;
    const int b    = (phys & 7) * 360 + (phys >> 3) / A_N;
    const int q    = (phys >> 3) % A_N;
    const int bq   = b * A_N + q;
    const int tid  = threadIdx.x;
    const int wave = tid >> 6, lane = tid & 63;
    const int row16 = lane & 15, kq4 = (lane >> 4) << 3, rb4 = (lane >> 4) << 2;

    // rel scan -> selk (exactly 32 entries >=0, offsets 0..31)
    for (int k = tid; k < M_N; k += 256) {
        int r = rel[(size_t)bq * M_N + k];
        if (r >= 0) selk[r] = k;
    }
    // qS row (1024 bf16) -> qsr rows 0..7; zero rows 8..15
    {
        short4v v = ((const short4v*)(qS + (size_t)bq * 1024))[tid];
        *(short4v*)&qsr[tid >> 5][(tid & 31) << 2] = v;
    }
    for (int g = tid; g < 1088; g += 256) ((short*)qsr)[1088 + g] = 0;
    peL[tid] = pe[(size_t)bq * 256 + tid];
    __syncthreads();

    // gather 32 m rows (fp32 -> bf16), write row-major + transposed
    #pragma unroll
    for (int i = 0; i < 4; ++i) {
        int f = (i << 8) + tid;
        int r = f & 31, c0 = (f >> 5) << 2;
        f32x4 v = *(const f32x4*)(m_token + ((size_t)b * M_N + selk[r]) * DIMC + c0);
        short4v t;
        t.x = f2b(v.x); t.y = f2b(v.y); t.z = f2b(v.z); t.w = f2b(v.w);
        *(short4v*)&mr[r][c0] = t;
        mT[c0 + 0][r] = t.x; mT[c0 + 1][r] = t.y;
        mT[c0 + 2][r] = t.z; mT[c0 + 3][r] = t.w;
    }
    __syncthreads();

    // score MFMA: wave -> (mtile = wave&1 keys, khalf = wave>>1 K-half)
    {
        const int mtile = wave & 1, khalf = wave >> 1;
        f32x4 sacc = {0.f, 0.f, 0.f, 0.f};
        #pragma unroll
        for (int ks = 0; ks < 2; ++ks) {
            const int kk = (khalf << 6) + (ks << 5);
            bf16x8v a = *(const bf16x8v*)&mr[(mtile << 4) + row16][kk + kq4];
            bf16x8v bb = *(const bf16x8v*)&qsr[row16][kk + kq4];
            sacc = __builtin_amdgcn_mfma_f32_16x16x32_bf16(a, bb, sacc, 0, 0, 0);
        }
        #pragma unroll
        for (int r = 0; r < 4; ++r)
            sc[khalf][(mtile << 4) + rb4 + r][row16] = sacc[r];
    }
    __syncthreads();

    // softmax over 32 keys: thread (h = tid>>5 in 0..7, r = tid&31)
    {
        const int h = tid >> 5, r = tid & 31;
        float s = sc[0][r][h] + sc[1][r][h] + peL[r * 8 + h];
        float mx = s;
        #pragma unroll
        for (int off = 16; off; off >>= 1) mx = fmaxf(mx, __shfl_xor(mx, off, 32));
        float e = __expf(s - mx);
        float su = e;
        #pragma unroll
        for (int off = 16; off; off >>= 1) su += __shfl_xor(su, off, 32);
        wts[h][r] = f2b(e / su);
    }
    __syncthreads();

    // combine MFMA: u[h, d] = sum_r w[h,r] * m[r,d]; wave handles 2 d-tiles
    {
        bf16x8v aw = *(const bf16x8v*)&wts[row16][kq4];
        #pragma unroll
        for (int j = 0; j < 2; ++j) {
            const int nt = (wave << 1) + j;
            bf16x8v bm_ = *(const bf16x8v*)&mT[(nt << 4) + row16][kq4];
            f32x4 cz = {0.f, 0.f, 0.f, 0.f};
            cz = __builtin_amdgcn_mfma_f32_16x16x32_bf16(aw, bm_, cz, 0, 0, 0);
            #pragma unroll
            for (int r = 0; r < 4; ++r) {
                int hh = rb4 + r;
                if (hh < 8) uL[hh][(nt << 4) + row16] = f2b(cz[r]);
            }
        }
    }
    __syncthreads();
    if (tid < 128) {
        int h = tid >> 4, c8 = (tid & 15) << 3;
        *(bf16x8v*)(u + (size_t)bq * 1024 + h * 128 + c8) = *(const bf16x8v*)&uL[h][c8];
    }
}

// ---------------------------------------------------------------------------
// Self attention: per (b,q) block, 3 selected of 10 agent rows of y (bf16).
// ---------------------------------------------------------------------------
__global__ __launch_bounds__(256) void attn_self(
    const short* __restrict__ ybf, const short* __restrict__ yS2,
    const float* __restrict__ pe, const int* __restrict__ rel,
    short* __restrict__ u2)
{
    __shared__ float yrows[3][132];
    __shared__ float ysr[1024];
    __shared__ int   selk[3];
    __shared__ float sw[8][3];
    const int phys = blockIdx.x;
    const int b    = (phys & 7) * 360 + (phys >> 3) / A_N;
    const int q    = (phys >> 3) % A_N;
    const int bq   = b * A_N + q;
    const int tid = threadIdx.x;

    if (tid < A_N) {
        int r = rel[(size_t)bq * A_N + tid];
        if (r >= 0) selk[r] = tid;
    }
    {
        short4v v = ((const short4v*)(yS2 + (size_t)bq * 1024))[tid];
        ysr[(tid << 2) + 0] = b2f(v.x);
        ysr[(tid << 2) + 1] = b2f(v.y);
        ysr[(tid << 2) + 2] = b2f(v.z);
        ysr[(tid << 2) + 3] = b2f(v.w);
    }
    __syncthreads();
    if (tid < 48) {
        int r = tid >> 4, c = (tid & 15) << 3;
        bf16x8v v = *(const bf16x8v*)(ybf + ((size_t)b * A_N + selk[r]) * DIMC + c);
        #pragma unroll
        for (int j = 0; j < 8; ++j) yrows[r][c + j] = b2f(v[j]);
    }
    __syncthreads();
    if (tid < 24) {
        int h = tid / 3, r = tid - h * 3;
        const float* qh = ysr + (h << 7);
        f32x4 p = {0.f, 0.f, 0.f, 0.f};
        #pragma unroll
        for (int d = 0; d < DIMC; d += 4)
            p += *(const f32x4*)(qh + d) * *(const f32x4*)&yrows[r][d];
        sw[h][r] = p.x + p.y + p.z + p.w + pe[((size_t)bq * 3 + r) * 8 + h];
    }
    __syncthreads();
    if (tid < 8) {
        float s0 = sw[tid][0], s1 = sw[tid][1], s2 = sw[tid][2];
        float mx = fmaxf(s0, fmaxf(s1, s2));
        float e0 = __expf(s0 - mx), e1 = __expf(s1 - mx), e2 = __expf(s2 - mx);
        float inv = 1.f / (e0 + e1 + e2);
        sw[tid][0] = e0 * inv; sw[tid][1] = e1 * inv; sw[tid][2] = e2 * inv;
    }
    __syncthreads();
    {
        const int h = tid >> 5, d0 = (tid << 2) & 127;
        f32x4 acc = sw[h][0] * *(const f32x4*)&yrows[0][d0]
                  + sw[h][1] * *(const f32x4*)&yrows[1][d0]
                  + sw[h][2] * *(const f32x4*)&yrows[2][d0];
        short4v t;
        t.x = f2b(acc.x); t.y = f2b(acc.y); t.z = f2b(acc.z); t.w = f2b(acc.w);
        *(short4v*)(u2 + (size_t)bq * 1024 + (tid << 2)) = t;
    }
}

// ---------------------------------------------------------------------------
extern "C" void kernel_launch(void* const* d_in, const int* in_sizes, int n_in,
                              void* d_out, int out_size, void* d_ws, size_t ws_size,
                              hipStream_t stream)
{
    const float* a_token = (const float*)d_in[0];
    const float* m_token = (const float*)d_in[1];
    const float* a2m_pe  = (const float*)d_in[2];
    const float* a_pe    = (const float*)d_in[3];
    const float* Wq      = (const float*)d_in[4];
    const float* Wk      = (const float*)d_in[5];
    const float* Wv      = (const float*)d_in[6];
    const float* Wcp     = (const float*)d_in[7];
    const float* Wc      = (const float*)d_in[8];
    const float* Wsp     = (const float*)d_in[9];
    const int*   a2m_rel = (const int*)d_in[10];
    const int*   a_rel   = (const int*)d_in[11];

    char* ws = (char*)d_ws;
    short* S1t  = (short*)(ws + 0);
    short* VP1t = (short*)(ws + 262144);
    short* S2t  = (short*)(ws + 524288);
    short* VP2t = (short*)(ws + 786432);
    short* buf1 = (short*)(ws + 1048576);                  // qS, later yS2  [28800][1024]
    short* buf2 = (short*)(ws + 1048576 + 58982400ull);    // u,  later u2   [28800][1024]
    short* ybf  = (short*)(ws + 1048576 + 2ull * 58982400ull); // y bf16 [28800][128]
    float* outp = (float*)d_out;

    precompute_mats<<<dim3(2048), dim3(256), 0, stream>>>(
        Wq, Wk, Wv, Wcp, Wc, Wsp, S1t, VP1t, S2t, VP2t);

    // qS = a_token @ S1   [28800,1024], K=128
    gemm_bt<true, false><<<dim3(8, 225), dim3(256), 0, stream>>>(
        (const void*)a_token, S1t, (void*)buf1, BQ_N, 1024, 128);

    attn_cross2<<<dim3(BQ_N), dim3(256), 0, stream>>>(
        m_token, buf1, a2m_pe, a2m_rel, buf2);

    // y = u @ VP1   [28800,128], K=1024
    gemm_bt64<false><<<dim3(1, 450), dim3(256), 0, stream>>>(
        buf2, VP1t, (void*)ybf, BQ_N, 128, 1024);

    // yS2 = y @ S2   [28800,1024], K=128
    gemm_bt<false, false><<<dim3(8, 225), dim3(256), 0, stream>>>(
        (const void*)ybf, S2t, (void*)buf1, BQ_N, 1024, 128);

    attn_self<<<dim3(BQ_N), dim3(256), 0, stream>>>(
        ybf, buf1, a_pe, a_rel, buf2);

    // out = u2 @ VP2   [28800,128], K=1024, fp32 -> d_out
    gemm_bt64<true><<<dim3(1, 450), dim3(256), 0, stream>>>(
        buf2, VP2t, (void*)outp, BQ_N, 128, 1024);
}

// Round 4
// 319.648 us; speedup vs baseline: 1.1981x; 1.1981x over previous
//
#include <hip/hip_runtime.h>
#include <hip/hip_bf16.h>

// CustomModel_60851096649964: two-stage biased top-k attention, folded weights.
// R4: exact R1 chain (known 300us), two isolated changes:
//  (1) attn_cross blocked per-b (10 queries/block) for m-row L1/L2 reuse
//  (2) a_token pre-converted to bf16 (gemm1 A-tile read 8x as bf16 not fp32)

typedef __attribute__((ext_vector_type(4))) float f32x4;
typedef __attribute__((ext_vector_type(8))) short bf16x8v;
typedef __attribute__((ext_vector_type(4))) short short4v;

#define BT_N 2880
#define A_N  10
#define M_N  350
#define BQ_N (BT_N * A_N)   // 28800
#define DIMC 128

static __device__ __forceinline__ short f2b(float x) {
    __hip_bfloat16 b = __float2bfloat16(x);
    return __builtin_bit_cast(short, b);
}
static __device__ __forceinline__ float b2f(short s) {
    unsigned u = ((unsigned)(unsigned short)s) << 16;
    return __builtin_bit_cast(float, u);
}

// ---------------------------------------------------------------------------
// K0: folded per-head matrices (bf16, transposed for B^T GEMM). Unchanged.
// ---------------------------------------------------------------------------
__global__ __launch_bounds__(256) void precompute_mats(
    const float* __restrict__ Wq, const float* __restrict__ Wk,
    const float* __restrict__ Wv, const float* __restrict__ Wcp,
    const float* __restrict__ Wc, const float* __restrict__ Wsp,
    short* __restrict__ S1t, short* __restrict__ VP1t,
    short* __restrict__ S2t, short* __restrict__ VP2t)
{
    int gid = blockIdx.x * 256 + threadIdx.x;
    int mat = gid >> 17;
    int idx = gid & 131071;
    float acc = 0.f;
    if (mat == 0) {
        int n = idx >> 7, c = idx & 127;
        int h = n >> 7, d = n & 127;
        #pragma unroll
        for (int t = 0; t < 16; ++t)
            acc += Wq[c * 128 + h * 16 + t] * Wk[d * 128 + h * 16 + t];
        S1t[idx] = f2b(acc * 0.25f);
    } else if (mat == 1) {
        int d = idx >> 10, o = idx & 1023;
        int h = o >> 7, c = o & 127;
        #pragma unroll
        for (int t = 0; t < 16; ++t)
            acc += Wv[c * 128 + h * 16 + t] * Wcp[(h * 16 + t) * 128 + d];
        VP1t[idx] = f2b(acc);
    } else if (mat == 2) {
        int n = idx >> 7, c = idx & 127;
        int h = n >> 7, d = n & 127;
        #pragma unroll
        for (int t = 0; t < 16; ++t)
            acc += Wc[c * 384 + h * 16 + t] * Wc[d * 384 + 128 + h * 16 + t];
        S2t[idx] = f2b(acc * 0.25f);
    } else {
        int d = idx >> 10, o = idx & 1023;
        int h = o >> 7, c = o & 127;
        #pragma unroll
        for (int t = 0; t < 16; ++t)
            acc += Wc[c * 384 + 256 + h * 16 + t] * Wsp[(h * 16 + t) * 128 + d];
        VP2t[idx] = f2b(acc);
    }
}

// ---------------------------------------------------------------------------
// a_token fp32 -> bf16 (8 elems/thread)
// ---------------------------------------------------------------------------
__global__ __launch_bounds__(256) void conv_bf16(
    const float* __restrict__ in, short* __restrict__ out)
{
    int i = blockIdx.x * 256 + threadIdx.x;   // 0 .. 460799
    f32x4 a = ((const f32x4*)in)[2 * i];
    f32x4 b = ((const f32x4*)in)[2 * i + 1];
    bf16x8v t;
    t[0] = f2b(a.x); t[1] = f2b(a.y); t[2] = f2b(a.z); t[3] = f2b(a.w);
    t[4] = f2b(b.x); t[5] = f2b(b.y); t[6] = f2b(b.z); t[7] = f2b(b.w);
    ((bf16x8v*)out)[i] = t;
}

// ---------------------------------------------------------------------------
// bf16 MFMA GEMM, C[M,N] = A[M,K] @ Bt^T. BM=BN=128, BK=64. (R1 kernel)
// ---------------------------------------------------------------------------
template<bool CF32>
__global__ __launch_bounds__(256) void gemm_bt(
    const short* __restrict__ Ap, const short* __restrict__ Bt,
    void* __restrict__ Cp, int M, int N, int K)
{
    __shared__ short As[128][72];
    __shared__ short Bs[128][72];
    const int tid  = threadIdx.x;
    const int bm   = blockIdx.y << 7, bn = blockIdx.x << 7;
    const int wave = tid >> 6, lane = tid & 63;
    const int wm   = (wave >> 1) << 6, wn = (wave & 1) << 6;
    const int row16 = lane & 15, kq = (lane >> 4) << 3;
    f32x4 acc[4][4] = {};

    for (int k0 = 0; k0 < K; k0 += 64) {
        #pragma unroll
        for (int i = 0; i < 4; ++i) {
            int g = (i << 8) + tid;
            int r = g >> 3, c = (g & 7) << 3;
            *(bf16x8v*)&As[r][c] = *(const bf16x8v*)(Ap + (size_t)(bm + r) * K + k0 + c);
        }
        #pragma unroll
        for (int i = 0; i < 4; ++i) {
            int g = (i << 8) + tid;
            int r = g >> 3, c = (g & 7) << 3;
            *(bf16x8v*)&Bs[r][c] = *(const bf16x8v*)(Bt + (size_t)(bn + r) * K + k0 + c);
        }
        __syncthreads();
        #pragma unroll
        for (int kk = 0; kk < 64; kk += 32) {
            bf16x8v afr[4], bfr[4];
            #pragma unroll
            for (int mi = 0; mi < 4; ++mi)
                afr[mi] = *(const bf16x8v*)&As[wm + (mi << 4) + row16][kq + kk];
            #pragma unroll
            for (int ni = 0; ni < 4; ++ni)
                bfr[ni] = *(const bf16x8v*)&Bs[wn + (ni << 4) + row16][kq + kk];
            #pragma unroll
            for (int mi = 0; mi < 4; ++mi)
                #pragma unroll
                for (int ni = 0; ni < 4; ++ni)
                    acc[mi][ni] = __builtin_amdgcn_mfma_f32_16x16x32_bf16(
                        afr[mi], bfr[ni], acc[mi][ni], 0, 0, 0);
        }
        __syncthreads();
    }

    const int col = lane & 15, rb = (lane >> 4) << 2;
    #pragma unroll
    for (int mi = 0; mi < 4; ++mi)
        #pragma unroll
        for (int ni = 0; ni < 4; ++ni)
            #pragma unroll
            for (int r = 0; r < 4; ++r) {
                int rr = bm + wm + (mi << 4) + rb + r;
                int cc = bn + wn + (ni << 4) + col;
                float v = acc[mi][ni][r];
                if (CF32) ((float*)Cp)[(size_t)rr * N + cc] = v;
                else      ((short*)Cp)[(size_t)rr * N + cc] = f2b(v);
            }
}

// ---------------------------------------------------------------------------
// Cross attention, per-b blocking: one block handles all 10 queries of batch b
// sequentially (R1 phase code verbatim inside a q-loop). m-row gathers of the
// 10 queries hit the same CU's L1/XCD L2 -> HBM m traffic ~472->~318 MB.
// ---------------------------------------------------------------------------
__global__ __launch_bounds__(256) void attn_cross_b(
    const float* __restrict__ m_token, const short* __restrict__ qS,
    const float* __restrict__ pe, const int* __restrict__ rel,
    short* __restrict__ u)
{
    __shared__ float mrows[32][132];
    __shared__ float qsr[1024];
    __shared__ int   selk[32];
    __shared__ float wts[8][32];
    __shared__ float peL[256];
    const int b   = blockIdx.x;
    const int tid = threadIdx.x;
    const float* mb = m_token + (size_t)b * M_N * DIMC;

    for (int q = 0; q < A_N; ++q) {
        const int bq = b * A_N + q;
        // phase A: selk scan, qS row -> f32, pe row
        for (int k = tid; k < M_N; k += 256) {
            int r = rel[(size_t)bq * M_N + k];
            if (r >= 0) selk[r] = k;
        }
        {
            short4v v = ((const short4v*)(qS + (size_t)bq * 1024))[tid];
            qsr[(tid << 2) + 0] = b2f(v.x);
            qsr[(tid << 2) + 1] = b2f(v.y);
            qsr[(tid << 2) + 2] = b2f(v.z);
            qsr[(tid << 2) + 3] = b2f(v.w);
        }
        peL[tid] = pe[(size_t)bq * 256 + tid];
        __syncthreads();
        // phase B: gather 32 m rows (fp32)
        #pragma unroll
        for (int i = 0; i < 4; ++i) {
            int f = (i << 8) + tid;
            int r = f >> 5, c = (f & 31) << 2;
            f32x4 v = *(const f32x4*)(mb + (size_t)selk[r] * DIMC + c);
            *(f32x4*)&mrows[r][c] = v;
        }
        __syncthreads();
        // phase C: scores + softmax (h = tid>>5, r = tid&31)
        {
            const int h = tid >> 5, r = tid & 31;
            const float* qh = qsr + (h << 7);
            f32x4 p = {0.f, 0.f, 0.f, 0.f};
            #pragma unroll
            for (int d = 0; d < DIMC; d += 4)
                p += *(const f32x4*)(qh + d) * *(const f32x4*)&mrows[r][d];
            float sc = p.x + p.y + p.z + p.w + peL[r * 8 + h];
            float mx = sc;
            #pragma unroll
            for (int off = 16; off; off >>= 1) mx = fmaxf(mx, __shfl_xor(mx, off, 32));
            float e = __expf(sc - mx);
            float s = e;
            #pragma unroll
            for (int off = 16; off; off >>= 1) s += __shfl_xor(s, off, 32);
            wts[h][r] = e / s;
        }
        __syncthreads();
        // phase D: weighted combine -> u (bf16)
        {
            const int h = tid >> 5, d0 = (tid << 2) & 127;
            f32x4 acc = {0.f, 0.f, 0.f, 0.f};
            #pragma unroll
            for (int r = 0; r < 32; ++r)
                acc += wts[h][r] * *(const f32x4*)&mrows[r][d0];
            short4v t;
            t.x = f2b(acc.x); t.y = f2b(acc.y); t.z = f2b(acc.z); t.w = f2b(acc.w);
            *(short4v*)(u + (size_t)bq * 1024 + (tid << 2)) = t;
        }
        __syncthreads();   // protect LDS before next query's phase A
    }
}

// ---------------------------------------------------------------------------
// Self attention: per (b,q) block (R1 verbatim, no swizzle).
// ---------------------------------------------------------------------------
__global__ __launch_bounds__(256) void attn_self(
    const short* __restrict__ ybf, const short* __restrict__ yS2,
    const float* __restrict__ pe, const int* __restrict__ rel,
    short* __restrict__ u2)
{
    __shared__ float yrows[3][132];
    __shared__ float ysr[1024];
    __shared__ int   selk[3];
    __shared__ float sw[8][3];
    const int bq = blockIdx.x;
    const int b  = bq / A_N;
    const int tid = threadIdx.x;

    if (tid < A_N) {
        int r = rel[(size_t)bq * A_N + tid];
        if (r >= 0) selk[r] = tid;
    }
    {
        short4v v = ((const short4v*)(yS2 + (size_t)bq * 1024))[tid];
        ysr[(tid << 2) + 0] = b2f(v.x);
        ysr[(tid << 2) + 1] = b2f(v.y);
        ysr[(tid << 2) + 2] = b2f(v.z);
        ysr[(tid << 2) + 3] = b2f(v.w);
    }
    __syncthreads();
    if (tid < 48) {
        int r = tid >> 4, c = (tid & 15) << 3;
        bf16x8v v = *(const bf16x8v*)(ybf + ((size_t)b * A_N + selk[r]) * DIMC + c);
        #pragma unroll
        for (int j = 0; j < 8; ++j) yrows[r][c + j] = b2f(v[j]);
    }
    __syncthreads();
    if (tid < 24) {
        int h = tid / 3, r = tid - h * 3;
        const float* qh = ysr + (h << 7);
        f32x4 p = {0.f, 0.f, 0.f, 0.f};
        #pragma unroll
        for (int d = 0; d < DIMC; d += 4)
            p += *(const f32x4*)(qh + d) * *(const f32x4*)&yrows[r][d];
        sw[h][r] = p.x + p.y + p.z + p.w + pe[((size_t)bq * 3 + r) * 8 + h];
    }
    __syncthreads();
    if (tid < 8) {
        float s0 = sw[tid][0], s1 = sw[tid][1], s2 = sw[tid][2];
        float mx = fmaxf(s0, fmaxf(s1, s2));
        float e0 = __expf(s0 - mx), e1 = __expf(s1 - mx), e2 = __expf(s2 - mx);
        float inv = 1.f / (e0 + e1 + e2);
        sw[tid][0] = e0 * inv; sw[tid][1] = e1 * inv; sw[tid][2] = e2 * inv;
    }
    __syncthreads();
    {
        const int h = tid >> 5, d0 = (tid << 2) & 127;
        f32x4 acc = sw[h][0] * *(const f32x4*)&yrows[0][d0]
                  + sw[h][1] * *(const f32x4*)&yrows[1][d0]
                  + sw[h][2] * *(const f32x4*)&yrows[2][d0];
        short4v t;
        t.x = f2b(acc.x); t.y = f2b(acc.y); t.z = f2b(acc.z); t.w = f2b(acc.w);
        *(short4v*)(u2 + (size_t)bq * 1024 + (tid << 2)) = t;
    }
}

// ---------------------------------------------------------------------------
extern "C" void kernel_launch(void* const* d_in, const int* in_sizes, int n_in,
                              void* d_out, int out_size, void* d_ws, size_t ws_size,
                              hipStream_t stream)
{
    const float* a_token = (const float*)d_in[0];
    const float* m_token = (const float*)d_in[1];
    const float* a2m_pe  = (const float*)d_in[2];
    const float* a_pe    = (const float*)d_in[3];
    const float* Wq      = (const float*)d_in[4];
    const float* Wk      = (const float*)d_in[5];
    const float* Wv      = (const float*)d_in[6];
    const float* Wcp     = (const float*)d_in[7];
    const float* Wc      = (const float*)d_in[8];
    const float* Wsp     = (const float*)d_in[9];
    const int*   a2m_rel = (const int*)d_in[10];
    const int*   a_rel   = (const int*)d_in[11];

    char* ws = (char*)d_ws;
    short* S1t  = (short*)(ws + 0);
    short* VP1t = (short*)(ws + 262144);
    short* S2t  = (short*)(ws + 524288);
    short* VP2t = (short*)(ws + 786432);
    short* buf1 = (short*)(ws + 1048576);                      // qS, later yS2  [28800][1024]
    short* buf2 = (short*)(ws + 1048576 + 58982400ull);        // u,  later u2   [28800][1024]
    short* ybf  = (short*)(ws + 1048576 + 2ull * 58982400ull); // y bf16 [28800][128]
    short* abf  = (short*)(ws + 1048576 + 2ull * 58982400ull + 7372800ull); // a_token bf16
    float* outp = (float*)d_out;

    precompute_mats<<<dim3(2048), dim3(256), 0, stream>>>(
        Wq, Wk, Wv, Wcp, Wc, Wsp, S1t, VP1t, S2t, VP2t);

    conv_bf16<<<dim3(1800), dim3(256), 0, stream>>>(a_token, abf);

    // qS = a @ S1   [28800,1024], K=128
    gemm_bt<false><<<dim3(8, 225), dim3(256), 0, stream>>>(
        abf, S1t, (void*)buf1, BQ_N, 1024, 128);

    attn_cross_b<<<dim3(BT_N), dim3(256), 0, stream>>>(
        m_token, buf1, a2m_pe, a2m_rel, buf2);

    // y = u @ VP1   [28800,128], K=1024
    gemm_bt<false><<<dim3(1, 225), dim3(256), 0, stream>>>(
        buf2, VP1t, (void*)ybf, BQ_N, 128, 1024);

    // yS2 = y @ S2   [28800,1024], K=128
    gemm_bt<false><<<dim3(8, 225), dim3(256), 0, stream>>>(
        ybf, S2t, (void*)buf1, BQ_N, 1024, 128);

    attn_self<<<dim3(BQ_N), dim3(256), 0, stream>>>(
        ybf, buf1, a_pe, a_rel, buf2);

    // out = u2 @ VP2   [28800,128], K=1024, fp32 -> d_out
    gemm_bt<true><<<dim3(1, 225), dim3(256), 0, stream>>>(
        buf2, VP2t, (void*)outp, BQ_N, 128, 1024);
}

// Round 5
// 294.822 us; speedup vs baseline: 1.2990x; 1.0842x over previous
//
#include <hip/hip_runtime.h>
#include <hip/hip_bf16.h>

// CustomModel_60851096649964: two-stage biased top-k attention, folded weights.
// R5: R1 chain + (a) a_token pre-converted bf16 for gemm1, (b) attn_cross with
// R1 internals but XCD-swizzled grid (10 queries of each b -> same XCD L2).

typedef __attribute__((ext_vector_type(4))) float f32x4;
typedef __attribute__((ext_vector_type(8))) short bf16x8v;
typedef __attribute__((ext_vector_type(4))) short short4v;

#define BT_N 2880
#define A_N  10
#define M_N  350
#define BQ_N (BT_N * A_N)   // 28800
#define DIMC 128

static __device__ __forceinline__ short f2b(float x) {
    __hip_bfloat16 b = __float2bfloat16(x);
    return __builtin_bit_cast(short, b);
}
static __device__ __forceinline__ float b2f(short s) {
    unsigned u = ((unsigned)(unsigned short)s) << 16;
    return __builtin_bit_cast(float, u);
}

// ---------------------------------------------------------------------------
// K0: folded per-head matrices (bf16, transposed for B^T GEMM). Unchanged.
// ---------------------------------------------------------------------------
__global__ __launch_bounds__(256) void precompute_mats(
    const float* __restrict__ Wq, const float* __restrict__ Wk,
    const float* __restrict__ Wv, const float* __restrict__ Wcp,
    const float* __restrict__ Wc, const float* __restrict__ Wsp,
    short* __restrict__ S1t, short* __restrict__ VP1t,
    short* __restrict__ S2t, short* __restrict__ VP2t)
{
    int gid = blockIdx.x * 256 + threadIdx.x;
    int mat = gid >> 17;
    int idx = gid & 131071;
    float acc = 0.f;
    if (mat == 0) {
        int n = idx >> 7, c = idx & 127;
        int h = n >> 7, d = n & 127;
        #pragma unroll
        for (int t = 0; t < 16; ++t)
            acc += Wq[c * 128 + h * 16 + t] * Wk[d * 128 + h * 16 + t];
        S1t[idx] = f2b(acc * 0.25f);
    } else if (mat == 1) {
        int d = idx >> 10, o = idx & 1023;
        int h = o >> 7, c = o & 127;
        #pragma unroll
        for (int t = 0; t < 16; ++t)
            acc += Wv[c * 128 + h * 16 + t] * Wcp[(h * 16 + t) * 128 + d];
        VP1t[idx] = f2b(acc);
    } else if (mat == 2) {
        int n = idx >> 7, c = idx & 127;
        int h = n >> 7, d = n & 127;
        #pragma unroll
        for (int t = 0; t < 16; ++t)
            acc += Wc[c * 384 + h * 16 + t] * Wc[d * 384 + 128 + h * 16 + t];
        S2t[idx] = f2b(acc * 0.25f);
    } else {
        int d = idx >> 10, o = idx & 1023;
        int h = o >> 7, c = o & 127;
        #pragma unroll
        for (int t = 0; t < 16; ++t)
            acc += Wc[c * 384 + 256 + h * 16 + t] * Wsp[(h * 16 + t) * 128 + d];
        VP2t[idx] = f2b(acc);
    }
}

// ---------------------------------------------------------------------------
// a_token fp32 -> bf16 (8 elems/thread)
// ---------------------------------------------------------------------------
__global__ __launch_bounds__(256) void conv_bf16(
    const float* __restrict__ in, short* __restrict__ out)
{
    int i = blockIdx.x * 256 + threadIdx.x;   // 0 .. 460799
    f32x4 a = ((const f32x4*)in)[2 * i];
    f32x4 b = ((const f32x4*)in)[2 * i + 1];
    bf16x8v t;
    t[0] = f2b(a.x); t[1] = f2b(a.y); t[2] = f2b(a.z); t[3] = f2b(a.w);
    t[4] = f2b(b.x); t[5] = f2b(b.y); t[6] = f2b(b.z); t[7] = f2b(b.w);
    ((bf16x8v*)out)[i] = t;
}

// ---------------------------------------------------------------------------
// bf16 MFMA GEMM, C[M,N] = A[M,K] @ Bt^T. BM=BN=128, BK=64.
// ---------------------------------------------------------------------------
template<bool CF32>
__global__ __launch_bounds__(256) void gemm_bt(
    const short* __restrict__ Ap, const short* __restrict__ Bt,
    void* __restrict__ Cp, int M, int N, int K)
{
    __shared__ short As[128][72];
    __shared__ short Bs[128][72];
    const int tid  = threadIdx.x;
    const int bm   = blockIdx.y << 7, bn = blockIdx.x << 7;
    const int wave = tid >> 6, lane = tid & 63;
    const int wm   = (wave >> 1) << 6, wn = (wave & 1) << 6;
    const int row16 = lane & 15, kq = (lane >> 4) << 3;
    f32x4 acc[4][4] = {};

    for (int k0 = 0; k0 < K; k0 += 64) {
        #pragma unroll
        for (int i = 0; i < 4; ++i) {
            int g = (i << 8) + tid;
            int r = g >> 3, c = (g & 7) << 3;
            *(bf16x8v*)&As[r][c] = *(const bf16x8v*)(Ap + (size_t)(bm + r) * K + k0 + c);
        }
        #pragma unroll
        for (int i = 0; i < 4; ++i) {
            int g = (i << 8) + tid;
            int r = g >> 3, c = (g & 7) << 3;
            *(bf16x8v*)&Bs[r][c] = *(const bf16x8v*)(Bt + (size_t)(bn + r) * K + k0 + c);
        }
        __syncthreads();
        #pragma unroll
        for (int kk = 0; kk < 64; kk += 32) {
            bf16x8v afr[4], bfr[4];
            #pragma unroll
            for (int mi = 0; mi < 4; ++mi)
                afr[mi] = *(const bf16x8v*)&As[wm + (mi << 4) + row16][kq + kk];
            #pragma unroll
            for (int ni = 0; ni < 4; ++ni)
                bfr[ni] = *(const bf16x8v*)&Bs[wn + (ni << 4) + row16][kq + kk];
            #pragma unroll
            for (int mi = 0; mi < 4; ++mi)
                #pragma unroll
                for (int ni = 0; ni < 4; ++ni)
                    acc[mi][ni] = __builtin_amdgcn_mfma_f32_16x16x32_bf16(
                        afr[mi], bfr[ni], acc[mi][ni], 0, 0, 0);
        }
        __syncthreads();
    }

    const int col = lane & 15, rb = (lane >> 4) << 2;
    #pragma unroll
    for (int mi = 0; mi < 4; ++mi)
        #pragma unroll
        for (int ni = 0; ni < 4; ++ni)
            #pragma unroll
            for (int r = 0; r < 4; ++r) {
                int rr = bm + wm + (mi << 4) + rb + r;
                int cc = bn + wn + (ni << 4) + col;
                float v = acc[mi][ni][r];
                if (CF32) ((float*)Cp)[(size_t)rr * N + cc] = v;
                else      ((short*)Cp)[(size_t)rr * N + cc] = f2b(v);
            }
}

// ---------------------------------------------------------------------------
// Cross attention: R1 internals verbatim, per-(b,q) block, XCD-swizzled grid
// so the 10 queries of each b run on the same XCD (shared L2 m-rows).
// ---------------------------------------------------------------------------
__global__ __launch_bounds__(256) void attn_cross(
    const float* __restrict__ m_token, const short* __restrict__ qS,
    const float* __restrict__ pe, const int* __restrict__ rel,
    short* __restrict__ u)
{
    __shared__ float mrows[32][132];
    __shared__ float qsr[1024];
    __shared__ int   selk[32];
    __shared__ float wts[8][32];
    // bijective: phys -> (xcd = phys&7 owns b-range xcd*360..xcd*360+359)
    const int phys = blockIdx.x;
    const int b    = (phys & 7) * 360 + (phys >> 3) / A_N;
    const int q    = (phys >> 3) % A_N;
    const int bq   = b * A_N + q;
    const int tid = threadIdx.x;

    const int* relrow = rel + (size_t)bq * M_N;
    for (int k = tid; k < M_N; k += 256) {
        int r = relrow[k];
        if (r >= 0) selk[r] = k;
    }
    {
        short4v v = ((const short4v*)(qS + (size_t)bq * 1024))[tid];
        qsr[(tid << 2) + 0] = b2f(v.x);
        qsr[(tid << 2) + 1] = b2f(v.y);
        qsr[(tid << 2) + 2] = b2f(v.z);
        qsr[(tid << 2) + 3] = b2f(v.w);
    }
    __syncthreads();
    #pragma unroll
    for (int i = 0; i < 4; ++i) {
        int f = (i << 8) + tid;
        int r = f >> 5, c = (f & 31) << 2;
        f32x4 v = *(const f32x4*)(m_token + ((size_t)b * M_N + selk[r]) * DIMC + c);
        *(f32x4*)&mrows[r][c] = v;
    }
    __syncthreads();
    {
        const int h = tid >> 5, r = tid & 31;
        const float* qh = qsr + (h << 7);
        f32x4 p = {0.f, 0.f, 0.f, 0.f};
        #pragma unroll
        for (int d = 0; d < DIMC; d += 4)
            p += *(const f32x4*)(qh + d) * *(const f32x4*)&mrows[r][d];
        float sc = p.x + p.y + p.z + p.w + pe[((size_t)bq * 32 + r) * 8 + h];
        float mx = sc;
        #pragma unroll
        for (int off = 16; off; off >>= 1) mx = fmaxf(mx, __shfl_xor(mx, off, 32));
        float e = __expf(sc - mx);
        float s = e;
        #pragma unroll
        for (int off = 16; off; off >>= 1) s += __shfl_xor(s, off, 32);
        wts[h][r] = e / s;
    }
    __syncthreads();
    {
        const int h = tid >> 5, d0 = (tid << 2) & 127;
        f32x4 acc = {0.f, 0.f, 0.f, 0.f};
        #pragma unroll
        for (int r = 0; r < 32; ++r)
            acc += wts[h][r] * *(const f32x4*)&mrows[r][d0];
        short4v t;
        t.x = f2b(acc.x); t.y = f2b(acc.y); t.z = f2b(acc.z); t.w = f2b(acc.w);
        *(short4v*)(u + (size_t)bq * 1024 + (tid << 2)) = t;
    }
}

// ---------------------------------------------------------------------------
// Self attention: per (b,q) block (R1 verbatim).
// ---------------------------------------------------------------------------
__global__ __launch_bounds__(256) void attn_self(
    const short* __restrict__ ybf, const short* __restrict__ yS2,
    const float* __restrict__ pe, const int* __restrict__ rel,
    short* __restrict__ u2)
{
    __shared__ float yrows[3][132];
    __shared__ float ysr[1024];
    __shared__ int   selk[3];
    __shared__ float sw[8][3];
    const int bq = blockIdx.x;
    const int b  = bq / A_N;
    const int tid = threadIdx.x;

    if (tid < A_N) {
        int r = rel[(size_t)bq * A_N + tid];
        if (r >= 0) selk[r] = tid;
    }
    {
        short4v v = ((const short4v*)(yS2 + (size_t)bq * 1024))[tid];
        ysr[(tid << 2) + 0] = b2f(v.x);
        ysr[(tid << 2) + 1] = b2f(v.y);
        ysr[(tid << 2) + 2] = b2f(v.z);
        ysr[(tid << 2) + 3] = b2f(v.w);
    }
    __syncthreads();
    if (tid < 48) {
        int r = tid >> 4, c = (tid & 15) << 3;
        bf16x8v v = *(const bf16x8v*)(ybf + ((size_t)b * A_N + selk[r]) * DIMC + c);
        #pragma unroll
        for (int j = 0; j < 8; ++j) yrows[r][c + j] = b2f(v[j]);
    }
    __syncthreads();
    if (tid < 24) {
        int h = tid / 3, r = tid - h * 3;
        const float* qh = ysr + (h << 7);
        f32x4 p = {0.f, 0.f, 0.f, 0.f};
        #pragma unroll
        for (int d = 0; d < DIMC; d += 4)
            p += *(const f32x4*)(qh + d) * *(const f32x4*)&yrows[r][d];
        sw[h][r] = p.x + p.y + p.z + p.w + pe[((size_t)bq * 3 + r) * 8 + h];
    }
    __syncthreads();
    if (tid < 8) {
        float s0 = sw[tid][0], s1 = sw[tid][1], s2 = sw[tid][2];
        float mx = fmaxf(s0, fmaxf(s1, s2));
        float e0 = __expf(s0 - mx), e1 = __expf(s1 - mx), e2 = __expf(s2 - mx);
        float inv = 1.f / (e0 + e1 + e2);
        sw[tid][0] = e0 * inv; sw[tid][1] = e1 * inv; sw[tid][2] = e2 * inv;
    }
    __syncthreads();
    {
        const int h = tid >> 5, d0 = (tid << 2) & 127;
        f32x4 acc = sw[h][0] * *(const f32x4*)&yrows[0][d0]
                  + sw[h][1] * *(const f32x4*)&yrows[1][d0]
                  + sw[h][2] * *(const f32x4*)&yrows[2][d0];
        short4v t;
        t.x = f2b(acc.x); t.y = f2b(acc.y); t.z = f2b(acc.z); t.w = f2b(acc.w);
        *(short4v*)(u2 + (size_t)bq * 1024 + (tid << 2)) = t;
    }
}

// ---------------------------------------------------------------------------
extern "C" void kernel_launch(void* const* d_in, const int* in_sizes, int n_in,
                              void* d_out, int out_size, void* d_ws, size_t ws_size,
                              hipStream_t stream)
{
    const float* a_token = (const float*)d_in[0];
    const float* m_token = (const float*)d_in[1];
    const float* a2m_pe  = (const float*)d_in[2];
    const float* a_pe    = (const float*)d_in[3];
    const float* Wq      = (const float*)d_in[4];
    const float* Wk      = (const float*)d_in[5];
    const float* Wv      = (const float*)d_in[6];
    const float* Wcp     = (const float*)d_in[7];
    const float* Wc      = (const float*)d_in[8];
    const float* Wsp     = (const float*)d_in[9];
    const int*   a2m_rel = (const int*)d_in[10];
    const int*   a_rel   = (const int*)d_in[11];

    char* ws = (char*)d_ws;
    short* S1t  = (short*)(ws + 0);
    short* VP1t = (short*)(ws + 262144);
    short* S2t  = (short*)(ws + 524288);
    short* VP2t = (short*)(ws + 786432);
    short* buf1 = (short*)(ws + 1048576);                      // qS, later yS2  [28800][1024]
    short* buf2 = (short*)(ws + 1048576 + 58982400ull);        // u,  later u2   [28800][1024]
    short* ybf  = (short*)(ws + 1048576 + 2ull * 58982400ull); // y bf16 [28800][128]
    short* abf  = (short*)(ws + 1048576 + 2ull * 58982400ull + 7372800ull); // a_token bf16
    float* outp = (float*)d_out;

    precompute_mats<<<dim3(2048), dim3(256), 0, stream>>>(
        Wq, Wk, Wv, Wcp, Wc, Wsp, S1t, VP1t, S2t, VP2t);

    conv_bf16<<<dim3(1800), dim3(256), 0, stream>>>(a_token, abf);

    // qS = a @ S1   [28800,1024], K=128
    gemm_bt<false><<<dim3(8, 225), dim3(256), 0, stream>>>(
        abf, S1t, (void*)buf1, BQ_N, 1024, 128);

    attn_cross<<<dim3(BQ_N), dim3(256), 0, stream>>>(
        m_token, buf1, a2m_pe, a2m_rel, buf2);

    // y = u @ VP1   [28800,128], K=1024
    gemm_bt<false><<<dim3(1, 225), dim3(256), 0, stream>>>(
        buf2, VP1t, (void*)ybf, BQ_N, 128, 1024);

    // yS2 = y @ S2   [28800,1024], K=128
    gemm_bt<false><<<dim3(8, 225), dim3(256), 0, stream>>>(
        ybf, S2t, (void*)buf1, BQ_N, 1024, 128);

    attn_self<<<dim3(BQ_N), dim3(256), 0, stream>>>(
        ybf, buf1, a_pe, a_rel, buf2);

    // out = u2 @ VP2   [28800,128], K=1024, fp32 -> d_out
    gemm_bt<true><<<dim3(1, 225), dim3(256), 0, stream>>>(
        buf2, VP2t, (void*)outp, BQ_N, 128, 1024);
}